// Round 1
// baseline (617.424 us; speedup 1.0000x reference)
//
#include <hip/hip_runtime.h>
#include <hip/hip_bf16.h>
#include <cstdint>

typedef __attribute__((ext_vector_type(8))) short bf16x8;
typedef __attribute__((ext_vector_type(4))) float f32x4;

#define BN_EPS 1e-5f

__device__ __forceinline__ unsigned short f2bf(float f) {
    unsigned int u = __float_as_uint(f);
    unsigned int r = (u + 0x7FFFu + ((u >> 16) & 1u)) >> 16;
    return (unsigned short)r;
}
// monotone float -> uint map (order-preserving), for atomicMax-based float max
__device__ __forceinline__ unsigned int encf(float f) {
    unsigned int u = __float_as_uint(f);
    return (u & 0x80000000u) ? ~u : (u | 0x80000000u);
}

// ---------------- fold: BN-fold, W23 = W2 @ (W3*s3), W4 -> bf16 B-frag-linear ----------------
__global__ void fold_kernel(const float* __restrict__ W1, const float* __restrict__ b1,
                            const float* __restrict__ g1, const float* __restrict__ be1,
                            const float* __restrict__ m1, const float* __restrict__ v1,
                            const float* __restrict__ W2, const float* __restrict__ b2,
                            const float* __restrict__ W3, const float* __restrict__ b3,
                            const float* __restrict__ g3, const float* __restrict__ be3,
                            const float* __restrict__ m3, const float* __restrict__ v3,
                            const float* __restrict__ W4,
                            float* __restrict__ W1f, float* __restrict__ b1f,
                            float* __restrict__ W23t, float* __restrict__ b23,
                            unsigned short* __restrict__ W4p) {
    int tid = blockIdx.x * blockDim.x + threadIdx.x; // 131072 threads
    if (tid < 131072) {
        // W4p flat = ((nt*4+kf)*64 + lane)*8 + j ; element = W4[k][col]
        int j = tid & 7, lane = (tid >> 3) & 63, kf = (tid >> 9) & 3, nt = tid >> 11;
        int col = nt * 16 + (lane & 15);
        int k = kf * 32 + (lane >> 4) * 8 + j;
        W4p[tid] = f2bf(W4[k * 1024 + col]);
    }
    if (tid < 8192) { // W23t[j][i] = sum_o W2[i][o]*W3[o][j]*s3[j]
        int jj = tid >> 6, i = tid & 63;
        float s3 = g3[jj] / sqrtf(v3[jj] + BN_EPS);
        float acc = 0.f;
        for (int o = 0; o < 64; ++o) acc += W2[i * 64 + o] * W3[o * 128 + jj];
        W23t[jj * 64 + i] = acc * s3;
    }
    if (tid < 128) { // b23[j] = (sum_o b2[o]W3[o][j] + b3[j] - m3[j])*s3[j] + be3[j]
        float s3 = g3[tid] / sqrtf(v3[tid] + BN_EPS);
        float acc = b3[tid] - m3[tid];
        for (int o = 0; o < 64; ++o) acc += b2[o] * W3[o * 128 + tid];
        b23[tid] = acc * s3 + be3[tid];
    }
    if (tid < 192) { // W1f = W1 * s1 (broadcast over fan_out)
        int o = tid % 64;
        float s1 = g1[o] / sqrtf(v1[o] + BN_EPS);
        W1f[tid] = W1[tid] * s1;
    }
    if (tid < 64) {
        float s1 = g1[tid] / sqrtf(v1[tid] + BN_EPS);
        b1f[tid] = (b1[tid] - m1[tid]) * s1 + be1[tid];
    }
}

// ---------------- per-point MLP -> h3 (bf16, A-fragment-linear per 64-point tile) ----------------
__global__ __launch_bounds__(256) void mlp_kernel(const float* __restrict__ x,
                                                  const float* __restrict__ W1f,
                                                  const float* __restrict__ b1f,
                                                  const float* __restrict__ W23t,
                                                  const float* __restrict__ b23,
                                                  unsigned short* __restrict__ h3,
                                                  long long pbase, int npts_round, long long Ntot) {
    int t = blockIdx.x * 256 + threadIdx.x;
    if (t >= npts_round) return;
    long long p = pbase + t;
    int row = threadIdx.x & 63;           // row within this wave's 64-point tile
    int tile = t >> 6;
    unsigned short* tbase = h3 + (size_t)tile * 8192; // 16 KB per tile
    int mt = row >> 4, r16 = row & 15;

    float h1[64];
    if (p < Ntot) {
        float x0 = x[p * 3 + 0], x1 = x[p * 3 + 1], x2 = x[p * 3 + 2];
#pragma unroll
        for (int o = 0; o < 64; ++o) {
            float v = fmaf(x0, W1f[o], fmaf(x1, W1f[64 + o], fmaf(x2, W1f[128 + o], b1f[o])));
            h1[o] = fmaxf(v, 0.f);
        }
    } else {
#pragma unroll
        for (int o = 0; o < 64; ++o) h1[o] = 0.f;
    }

    for (int jb = 0; jb < 16; ++jb) {
        alignas(16) unsigned short buf[8];
#pragma unroll
        for (int jj = 0; jj < 8; ++jj) {
            int j = jb * 8 + jj;
            float v = b23[j];
            const float* wrow = W23t + j * 64;
#pragma unroll
            for (int i = 0; i < 64; ++i) v = fmaf(h1[i], wrow[i], v);
            buf[jj] = f2bf(fmaxf(v, 0.f));
        }
        int j0 = jb * 8;
        int kf = j0 >> 5, sub = (j0 >> 3) & 3;
        // A-frag slot: ((mt*4+kf)*64 + sub*16 + r16) -> 8 bf16 (16 B)
        *reinterpret_cast<uint4*>(tbase + (size_t)((mt * 4 + kf) * 64 + sub * 16 + r16) * 8) =
            *reinterpret_cast<const uint4*>(buf);
    }
}

// ---------------- h3 @ W4 + b4, fused segment-max (ordered-int atomicMax) ----------------
__global__ __launch_bounds__(256) void gemm_max_kernel(const unsigned short* __restrict__ h3,
                                                       const unsigned short* __restrict__ W4p,
                                                       const float* __restrict__ b4,
                                                       const int* __restrict__ batch,
                                                       unsigned int* __restrict__ out,
                                                       long long pbase, int ntiles, long long Ntot) {
    int wave = blockIdx.x * 4 + (threadIdx.x >> 6);
    if (wave >= ntiles) return;
    int lane = threadIdx.x & 63;
    long long p0 = pbase + (long long)wave * 64;
    const unsigned short* tb = h3 + (size_t)wave * 8192;

    bf16x8 a[4][4];
#pragma unroll
    for (int mt = 0; mt < 4; ++mt)
#pragma unroll
        for (int kf = 0; kf < 4; ++kf)
            a[mt][kf] = *reinterpret_cast<const bf16x8*>(tb + (size_t)((mt * 4 + kf) * 64 + lane) * 8);

    long long plast = p0 + 63; if (plast > Ntot - 1) plast = Ntot - 1;
    int gfirst = batch[(p0 < Ntot) ? p0 : (Ntot - 1)];
    int glast = batch[plast];
    bool fast = (gfirst == glast) && (p0 + 63 < Ntot);

    int grow[16];
    if (!fast) {
#pragma unroll
        for (int mt = 0; mt < 4; ++mt)
#pragma unroll
            for (int r = 0; r < 4; ++r) {
                long long pp = p0 + mt * 16 + (lane >> 4) * 4 + r;
                grow[mt * 4 + r] = (pp < Ntot) ? batch[pp] : -1;
            }
    }

    for (int nt = 0; nt < 64; ++nt) {
        bf16x8 bq[4];
#pragma unroll
        for (int kf = 0; kf < 4; ++kf)
            bq[kf] = *reinterpret_cast<const bf16x8*>(W4p + (size_t)((nt * 4 + kf) * 64 + lane) * 8);
        f32x4 acc[4];
#pragma unroll
        for (int mt = 0; mt < 4; ++mt) acc[mt] = (f32x4){0.f, 0.f, 0.f, 0.f};
#pragma unroll
        for (int kf = 0; kf < 4; ++kf)
#pragma unroll
            for (int mt = 0; mt < 4; ++mt)
                acc[mt] = __builtin_amdgcn_mfma_f32_16x16x32_bf16(a[mt][kf], bq[kf], acc[mt], 0, 0, 0);

        int col = nt * 16 + (lane & 15);
        float bias = b4[col];
        if (fast) {
            float m = acc[0][0];
#pragma unroll
            for (int mt = 0; mt < 4; ++mt)
#pragma unroll
                for (int r = 0; r < 4; ++r) m = fmaxf(m, acc[mt][r]);
            m = fmaxf(m, __shfl_xor(m, 16));
            m = fmaxf(m, __shfl_xor(m, 32));
            if (lane < 16) atomicMax(&out[gfirst * 1024 + col], encf(m + bias));
        } else {
#pragma unroll
            for (int mt = 0; mt < 4; ++mt)
#pragma unroll
                for (int r = 0; r < 4; ++r) {
                    int g = grow[mt * 4 + r];
                    if (g >= 0) atomicMax(&out[g * 1024 + col], encf(acc[mt][r] + bias));
                }
        }
    }
}

__global__ void init_out(unsigned int* out, int n) {
    int t = blockIdx.x * 256 + threadIdx.x;
    if (t < n) out[t] = 0x007FFFFFu; // encf(-inf)
}
__global__ void decode_out(unsigned int* out, int n) {
    int t = blockIdx.x * 256 + threadIdx.x;
    if (t < n) {
        unsigned int e = out[t];
        out[t] = (e & 0x80000000u) ? (e & 0x7FFFFFFFu) : ~e;
    }
}

extern "C" void kernel_launch(void* const* d_in, const int* in_sizes, int n_in,
                              void* d_out, int out_size, void* d_ws, size_t ws_size,
                              hipStream_t stream) {
    const float* x   = (const float*)d_in[0];
    const int* batch = (const int*)d_in[1];
    const float* W1  = (const float*)d_in[2];
    const float* b1  = (const float*)d_in[3];
    const float* g1  = (const float*)d_in[4];
    const float* be1 = (const float*)d_in[5];
    const float* m1  = (const float*)d_in[6];
    const float* v1  = (const float*)d_in[7];
    const float* W2  = (const float*)d_in[8];
    const float* b2  = (const float*)d_in[9];
    const float* W3  = (const float*)d_in[10];
    const float* b3  = (const float*)d_in[11];
    const float* g3  = (const float*)d_in[12];
    const float* be3 = (const float*)d_in[13];
    const float* m3  = (const float*)d_in[14];
    const float* v3  = (const float*)d_in[15];
    const float* W4  = (const float*)d_in[16];
    const float* b4  = (const float*)d_in[17];

    long long N = in_sizes[1];

    char* ws = (char*)d_ws;
    unsigned short* W4p = (unsigned short*)(ws + 0);        // 262144 B
    float* W1f  = (float*)(ws + 262144);                    // 768 B
    float* b1f  = (float*)(ws + 263168);                    // 256 B
    float* W23t = (float*)(ws + 264192);                    // 32768 B
    float* b23  = (float*)(ws + 296960);                    // 512 B
    unsigned short* h3 = (unsigned short*)(ws + 1048576);   // bf16 frag-linear tiles

    fold_kernel<<<512, 256, 0, stream>>>(W1, b1, g1, be1, m1, v1, W2, b2, W3, b3, g3, be3, m3, v3,
                                         W4, W1f, b1f, W23t, b23, W4p);
    init_out<<<(out_size + 255) / 256, 256, 0, stream>>>((unsigned int*)d_out, out_size);

    size_t avail = (ws_size > 1048576) ? ws_size - 1048576 : 0;
    long long chunk = (long long)(avail / 16384) * 64; // points per chunk
    chunk = (chunk / 256) * 256;                       // multiple of 256
    long long ncap = ((N + 255) / 256) * 256;
    if (chunk > ncap) chunk = ncap;
    if (chunk < 256) chunk = 256; // safety (ws expected to be ample)

    for (long long base = 0; base < N; base += chunk) {
        long long npts = N - base; if (npts > chunk) npts = chunk;
        int ntiles = (int)((npts + 63) / 64);
        int nround = ntiles * 64;
        int blocks1 = (nround + 255) / 256;
        mlp_kernel<<<blocks1, 256, 0, stream>>>(x, W1f, b1f, W23t, b23, h3, base, blocks1 * 256, N);
        int blocks2 = (ntiles + 3) / 4;
        gemm_max_kernel<<<blocks2, 256, 0, stream>>>(h3, W4p, b4, batch, (unsigned int*)d_out,
                                                     base, ntiles, N);
    }
    decode_out<<<(out_size + 255) / 256, 256, 0, stream>>>((unsigned int*)d_out, out_size);
}